// Round 3
// baseline (724.129 us; speedup 1.0000x reference)
//
#include <hip/hip_runtime.h>
#include <hip/hip_bf16.h>

typedef unsigned short u16;
typedef __attribute__((ext_vector_type(8))) short bf16x8;   // 8 bf16 = 4 VGPRs
typedef __attribute__((ext_vector_type(4))) float f32x4;

#define EPSN 1e-9f

// ---------- helpers ----------

__device__ __forceinline__ u16 f2bf(float f) {
    union { float f; unsigned int u; } c; c.f = f;
    unsigned int u = c.u;
    unsigned int r = (u + 0x7FFFu + ((u >> 16) & 1u)) >> 16;   // RNE
    return (u16)r;
}

__device__ __forceinline__ void load16_to_lds(const void* g, void* l) {
    __builtin_amdgcn_global_load_lds(
        (const __attribute__((address_space(1))) void*)g,
        (__attribute__((address_space(3))) void*)l,
        16, 0, 0);
}

// ---------- K1: per-row L2 normalize + cast to bf16, wave-per-row, X and W fused ----
// One 64-lane wave per row (ncols <= 2048: 8 float4 per lane). No LDS, no barriers.
__global__ __launch_bounds__(256) void normalize_cast2(
    const float* __restrict__ X, const float* __restrict__ W,
    u16* __restrict__ XO, u16* __restrict__ WO, int ncols, int nxrows, int nrt) {
    const int lane = threadIdx.x & 63;
    const int r = blockIdx.x * 4 + (threadIdx.x >> 6);
    if (r >= nrt) return;
    const float* src; u16* dst; size_t row;
    if (r < nxrows) { src = X; dst = XO; row = r; }
    else            { src = W; dst = WO; row = r - nxrows; }

    const float4* xr = (const float4*)(src + row * (size_t)ncols);
    const int nq = ncols >> 2;

    float4 v[8];
    float ss = 0.f;
    #pragma unroll
    for (int q = 0; q < 8; ++q) {
        int i = lane + q * 64;
        if (i < nq) {
            v[q] = xr[i];
            ss += v[q].x*v[q].x + v[q].y*v[q].y + v[q].z*v[q].z + v[q].w*v[q].w;
        }
    }
    #pragma unroll
    for (int o = 32; o > 0; o >>= 1) ss += __shfl_xor(ss, o);
    const float s = 1.f / (sqrtf(ss) + EPSN);

    ushort4* yr = (ushort4*)(dst + row * (size_t)ncols);
    #pragma unroll
    for (int q = 0; q < 8; ++q) {
        int i = lane + q * 64;
        if (i < nq) {
            ushort4 o4;
            o4.x = f2bf(v[q].x * s); o4.y = f2bf(v[q].y * s);
            o4.z = f2bf(v[q].z * s); o4.w = f2bf(v[q].w * s);
            yr[i] = o4;
        }
    }
}

// ---------- K2: persistent-block 128x128 bf16 MFMA GEMM with FULLY fused softhebb ----
// GEMM core = the proven 2-phase 128^2 kernel (round-0, 156 us). New: persistent
// grid of 512 blocks (co-resident: 32KB LDS -> 5 blocks/CU capacity, need 2/CU;
// every block starts unconditionally, so the per-panel spin below cannot deadlock).
// Each block handles `iters` tiles; iteration j covers a contiguous, panel-complete
// range of tiles (nblk % ntn == 0, tiles % nblk == 0), so each row-panel's ntn
// contributor tiles are all processed in the same iteration -> spin release is
// guaranteed by induction over iterations.
// Per tile: u = relu(a)^lam * exp(lp) in regs -> rowsum atomics -> release fence ->
// ticket -> spin (agent-scope atomic load) -> acquire fence -> coherent rowsum
// read -> scale regs -> single final store of y. No Ul intermediate, no finalize.
__global__ __launch_bounds__(256, 2) void gemm_softhebb(
    const u16* __restrict__ A, const u16* __restrict__ B,
    const float* __restrict__ logprior, const float* __restrict__ lambp,
    float* __restrict__ Y, float* __restrict__ rowsum, unsigned int* __restrict__ cnt,
    int M, int N, int K, int iters) {
    __shared__ __align__(16) u16 lA[128 * 64];
    __shared__ __align__(16) u16 lB[128 * 64];

    const int tid  = threadIdx.x;
    const int lane = tid & 63;
    const int wm   = (tid >> 6) & 1;   // wave row (0..1)
    const int wn   = tid >> 7;         // wave col (0..1)
    const int ntn  = N >> 7;

    // XCD-aware persistent-block id swizzle: XCD x owns a contiguous id chunk so the
    // 4 row-panels it completes per iteration share A-slices in its L2.
    const int nblk = gridDim.x;
    int b = blockIdx.x;
    if ((nblk & 7) == 0) b = (b & 7) * (nblk >> 3) + (b >> 3);

    // staging geometry: chunk c = p*256+tid; row=c>>3, slot=c&7, global kchunk=slot^(row&7)
    int roff[4], coff[4], lo4[4];
    #pragma unroll
    for (int p = 0; p < 4; ++p) {
        int c = p * 256 + tid;
        int r = c >> 3;
        roff[p] = r;
        coff[p] = ((c & 7) ^ (r & 7)) * 8;
        lo4[p]  = c * 8;
    }

    const float lam = *lambp;
    const bool lam4 = (lam == 4.0f);

    for (int it = 0; it < iters; ++it) {
        const int g   = it * nblk + b;
        const int tm  = g / ntn;
        const int tn  = g - tm * ntn;
        const int row0 = tm << 7;
        const int col0 = tn << 7;

        f32x4 acc[4][4] = {};

        for (int k0 = 0; k0 < K; k0 += 64) {
            #pragma unroll
            for (int p = 0; p < 4; ++p) {
                load16_to_lds(A + (size_t)(row0 + roff[p]) * K + coff[p] + k0, &lA[lo4[p]]);
                load16_to_lds(B + (size_t)(col0 + roff[p]) * K + coff[p] + k0, &lB[lo4[p]]);
            }
            __syncthreads();

            #pragma unroll
            for (int s = 0; s < 2; ++s) {
                const int pos = (((s << 2) + (lane >> 4)) ^ (lane & 7)) * 8;
                bf16x8 af[4], bfr[4];
                #pragma unroll
                for (int i = 0; i < 4; ++i) {
                    int r = wm * 64 + i * 16 + (lane & 15);
                    af[i] = *(const bf16x8*)&lA[r * 64 + pos];
                }
                #pragma unroll
                for (int j = 0; j < 4; ++j) {
                    int r = wn * 64 + j * 16 + (lane & 15);
                    bfr[j] = *(const bf16x8*)&lB[r * 64 + pos];
                }
                #pragma unroll
                for (int i = 0; i < 4; ++i)
                    #pragma unroll
                    for (int j = 0; j < 4; ++j)
                        acc[i][j] = __builtin_amdgcn_mfma_f32_16x16x32_bf16(
                            af[i], bfr[j], acc[i][j], 0, 0, 0);
            }
            __syncthreads();
        }

        // ---- epilogue part 1: u = relu(a)^lam * exp(logprior); rowsum atomics ----
        // C/D layout: col = lane&15, row = (lane>>4)*4 + p   [m89/m91 verified]
        float el[4];
        #pragma unroll
        for (int j = 0; j < 4; ++j)
            el[j] = __expf(logprior[col0 + wn * 64 + j * 16 + (lane & 15)]);

        #pragma unroll
        for (int i = 0; i < 4; ++i) {
            #pragma unroll
            for (int p = 0; p < 4; ++p) {
                const int m = row0 + wm * 64 + i * 16 + (lane >> 4) * 4 + p;
                float rs = 0.f;
                #pragma unroll
                for (int j = 0; j < 4; ++j) {
                    float a = acc[i][j][p];
                    float u = 0.f;
                    if (a > 0.f) {
                        float pw;
                        if (lam4) { float a2 = a * a; pw = a2 * a2; }
                        else      { pw = __powf(a, lam); }
                        u = pw * el[j];
                    }
                    acc[i][j][p] = u;
                    rs += u;
                }
                rs += __shfl_xor(rs, 1);
                rs += __shfl_xor(rs, 2);
                rs += __shfl_xor(rs, 4);
                rs += __shfl_xor(rs, 8);
                if ((lane & 15) == 0) atomicAdd(&rowsum[m], rs);
            }
        }

        // ---- panel barrier: release -> ticket -> spin -> acquire ----
        __threadfence();                    // release this block's rowsum atomics
        __syncthreads();                    // all threads fenced before the ticket
        if (tid == 0) {
            atomicAdd(&cnt[tm], 1u);
            while (__hip_atomic_load(&cnt[tm], __ATOMIC_RELAXED,
                                     __HIP_MEMORY_SCOPE_AGENT) < (unsigned)ntn)
                __builtin_amdgcn_s_sleep(2);
        }
        __syncthreads();
        __threadfence();                    // acquire

        // ---- epilogue part 2: scale register tile by 1/(rowsum+eps), store y ----
        #pragma unroll
        for (int i = 0; i < 4; ++i) {
            #pragma unroll
            for (int p = 0; p < 4; ++p) {
                const int m = row0 + wm * 64 + i * 16 + (lane >> 4) * 4 + p;
                const float inv = 1.f / (__hip_atomic_load(&rowsum[m], __ATOMIC_RELAXED,
                                          __HIP_MEMORY_SCOPE_AGENT) + EPSN);
                float* outrow = Y + (size_t)m * N + col0 + wn * 64 + (lane & 15);
                #pragma unroll
                for (int j = 0; j < 4; ++j)
                    outrow[j * 16] = acc[i][j][p] * inv;
            }
        }
        // LDS reuse next iteration is safe: all lds reads ended before the K-loop's
        // final __syncthreads, and the spin's __syncthreads re-synced the block.
    }
}

// ---------- launch ----------
static inline size_t align256(size_t x) { return (x + 255) & ~(size_t)255; }

extern "C" void kernel_launch(void* const* d_in, const int* in_sizes, int n_in,
                              void* d_out, int out_size, void* d_ws, size_t ws_size,
                              hipStream_t stream) {
    const float* x        = (const float*)d_in[0];
    const float* w        = (const float*)d_in[1];
    const float* logprior = (const float*)d_in[2];
    const float* lamb     = (const float*)d_in[3];
    const int OUT = in_sizes[2];                // 2048
    const int IN  = in_sizes[1] / OUT;          // 2048
    const int B   = in_sizes[0] / IN;           // 16384
    float* out = (float*)d_out;

    const int ntm = B / 128, ntn = OUT / 128;   // 128, 16
    const int tiles = ntm * ntn;                // 2048

    char* ws = (char*)d_ws;
    size_t off = 0;
    u16* xn = (u16*)(ws + off);            off += align256((size_t)B * IN * sizeof(u16));
    u16* wn = (u16*)(ws + off);            off += align256((size_t)OUT * IN * sizeof(u16));
    float* rowsum = (float*)(ws + off);    off += align256((size_t)B * sizeof(float));
    unsigned int* cnt = (unsigned int*)(ws + off); off += align256((size_t)ntm * sizeof(unsigned int));

    // rowsum and cnt are contiguous (incl. alignment padding): one memset clears both
    hipMemsetAsync(rowsum, 0, (size_t)((char*)(cnt + ntm) - (char*)rowsum), stream);

    const int nrt = B + OUT;
    normalize_cast2<<<(nrt + 3) / 4, 256, 0, stream>>>(x, w, xn, wn, IN, B, nrt);

    // persistent grid: 512 blocks (co-resident), panel-complete per iteration
    // (requires nblk % ntn == 0 and tiles % nblk == 0; holds for this shape)
    const int nblk = 512;
    const int iters = tiles / nblk;             // 4
    gemm_softhebb<<<nblk, 256, 0, stream>>>(xn, wn, logprior, lamb, out, rowsum, cnt,
                                            B, OUT, IN, iters);
}

// Round 4
// 426.723 us; speedup vs baseline: 1.6970x; 1.6970x over previous
//
#include <hip/hip_runtime.h>
#include <hip/hip_bf16.h>

typedef unsigned short u16;
typedef __attribute__((ext_vector_type(8))) short bf16x8;   // 8 bf16 = 4 VGPRs
typedef __attribute__((ext_vector_type(4))) float f32x4;

#define EPSN 1e-9f

// ---------- helpers ----------

__device__ __forceinline__ u16 f2bf(float f) {
    union { float f; unsigned int u; } c; c.f = f;
    unsigned int u = c.u;
    unsigned int r = (u + 0x7FFFu + ((u >> 16) & 1u)) >> 16;   // RNE
    return (u16)r;
}

__device__ __forceinline__ void load16_to_lds(const void* g, void* l) {
    __builtin_amdgcn_global_load_lds(
        (const __attribute__((address_space(1))) void*)g,
        (__attribute__((address_space(3))) void*)l,
        16, 0, 0);
}

// ---------- K1: per-row L2 normalize + cast to bf16, wave-per-row, X and W fused ----
// One 64-lane wave per row (ncols <= 2048: 8 float4 per lane). No LDS, no barriers.
__global__ __launch_bounds__(256) void normalize_cast2(
    const float* __restrict__ X, const float* __restrict__ W,
    u16* __restrict__ XO, u16* __restrict__ WO, int ncols, int nxrows, int nrt) {
    const int lane = threadIdx.x & 63;
    const int r = blockIdx.x * 4 + (threadIdx.x >> 6);
    if (r >= nrt) return;
    const float* src; u16* dst; size_t row;
    if (r < nxrows) { src = X; dst = XO; row = r; }
    else            { src = W; dst = WO; row = r - nxrows; }

    const float4* xr = (const float4*)(src + row * (size_t)ncols);
    const int nq = ncols >> 2;

    float4 v[8];
    float ss = 0.f;
    #pragma unroll
    for (int q = 0; q < 8; ++q) {
        int i = lane + q * 64;
        if (i < nq) {
            v[q] = xr[i];
            ss += v[q].x*v[q].x + v[q].y*v[q].y + v[q].z*v[q].z + v[q].w*v[q].w;
        }
    }
    #pragma unroll
    for (int o = 32; o > 0; o >>= 1) ss += __shfl_xor(ss, o);
    const float s = 1.f / (sqrtf(ss) + EPSN);

    ushort4* yr = (ushort4*)(dst + row * (size_t)ncols);
    #pragma unroll
    for (int q = 0; q < 8; ++q) {
        int i = lane + q * 64;
        if (i < nq) {
            ushort4 o4;
            o4.x = f2bf(v[q].x * s); o4.y = f2bf(v[q].y * s);
            o4.z = f2bf(v[q].z * s); o4.w = f2bf(v[q].w * s);
            yr[i] = o4;
        }
    }
}

// ---------- K2: bf16 MFMA GEMM (A[M,K] * B[N,K]^T) + fused relu/pow epilogue ----------
// PROVEN round-0 core (156.6 us, MfmaUtil 40%): 128x128 tile, BK=64, 4 waves each
// computing 64x64 via 4x4 grid of 16x16x32 MFMA. LDS XOR-swizzle: chunk (row, kc)
// of 8 bf16 stored at position kc ^ (row&7) -> global_load_lds stays contiguous,
// ds_read_b128 is 2-way max (measured 0 bank conflicts).
// Only change vs round-0: exp(logprior) computed inline (drops prep_explp launch).
#define BK 64

__global__ __launch_bounds__(256, 2) void gemm_softhebb(
    const u16* __restrict__ A, const u16* __restrict__ B,
    const float* __restrict__ logprior, const float* __restrict__ lambp,
    float* __restrict__ Ul, float* __restrict__ rowsum,
    int M, int N, int K) {
    __shared__ __align__(16) u16 lA[128 * BK];
    __shared__ __align__(16) u16 lB[128 * BK];

    const int tid  = threadIdx.x;
    const int lane = tid & 63;
    const int wm   = (tid >> 6) & 1;   // wave row (0..1)
    const int wn   = tid >> 7;         // wave col (0..1)
    const int row0 = blockIdx.y * 128;
    const int col0 = blockIdx.x * 128;

    f32x4 acc[4][4] = {};

    // staging indices: chunk c = p*256+tid; row=c>>3, stored pos=c&7,
    // global kchunk = (c&7) ^ (row&7)
    const u16* ap[4];
    const u16* bp[4];
    #pragma unroll
    for (int p = 0; p < 4; ++p) {
        int c = p * 256 + tid;
        int r = c >> 3;
        int o = ((c & 7) ^ (r & 7)) * 8;
        ap[p] = A + (size_t)(row0 + r) * K + o;
        bp[p] = B + (size_t)(col0 + r) * K + o;
    }

    for (int k0 = 0; k0 < K; k0 += BK) {
        #pragma unroll
        for (int p = 0; p < 4; ++p) {
            int c = p * 256 + tid;
            load16_to_lds(ap[p] + k0, &lA[c * 8]);
            load16_to_lds(bp[p] + k0, &lB[c * 8]);
        }
        __syncthreads();

        #pragma unroll
        for (int s = 0; s < 2; ++s) {
            // fragment row r has (r&7)==(lane&7); kchunk = s*4 + (lane>>4)
            const int pos = (((s << 2) + (lane >> 4)) ^ (lane & 7)) * 8;
            bf16x8 af[4], bfr[4];
            #pragma unroll
            for (int i = 0; i < 4; ++i) {
                int r = wm * 64 + i * 16 + (lane & 15);
                af[i] = *(const bf16x8*)&lA[r * 64 + pos];
            }
            #pragma unroll
            for (int j = 0; j < 4; ++j) {
                int r = wn * 64 + j * 16 + (lane & 15);
                bfr[j] = *(const bf16x8*)&lB[r * 64 + pos];
            }
            #pragma unroll
            for (int i = 0; i < 4; ++i)
                #pragma unroll
                for (int j = 0; j < 4; ++j)
                    acc[i][j] = __builtin_amdgcn_mfma_f32_16x16x32_bf16(
                        af[i], bfr[j], acc[i][j], 0, 0, 0);
        }
        __syncthreads();
    }

    // epilogue: u = relu(a); ul = u^lam * exp(logprior); write + row partial sums
    // C/D layout: col = lane&15, row = (lane>>4)*4 + p   [m89/m91 verified]
    const float lam = *lambp;
    const bool lam4 = (lam == 4.0f);
    float el[4];
    #pragma unroll
    for (int j = 0; j < 4; ++j)
        el[j] = __expf(logprior[col0 + wn * 64 + j * 16 + (lane & 15)]);

    #pragma unroll
    for (int i = 0; i < 4; ++i) {
        #pragma unroll
        for (int p = 0; p < 4; ++p) {
            const int m = row0 + wm * 64 + i * 16 + (lane >> 4) * 4 + p;
            float* outrow = Ul + (size_t)m * N + col0 + wn * 64 + (lane & 15);
            float rs = 0.f;
            #pragma unroll
            for (int j = 0; j < 4; ++j) {
                float a = acc[i][j][p];
                float u = 0.f;
                if (a > 0.f) {
                    float pw;
                    if (lam4) { float a2 = a * a; pw = a2 * a2; }
                    else      { pw = __powf(a, lam); }
                    u = pw * el[j];
                }
                outrow[j * 16] = u;
                rs += u;
            }
            // reduce across the 16 lanes sharing this row (lanes differ in low 4 bits)
            rs += __shfl_xor(rs, 1);
            rs += __shfl_xor(rs, 2);
            rs += __shfl_xor(rs, 4);
            rs += __shfl_xor(rs, 8);
            if ((lane & 15) == 0) atomicAdd(&rowsum[m], rs);
        }
    }
}

// ---------- K3: y = ul / (rowsum + eps), grid-strided: 8 rows per block ----------
__global__ __launch_bounds__(256) void finalize_row(
    float* __restrict__ Ul, const float* __restrict__ rowsum, int nq) {
    #pragma unroll
    for (int r = 0; r < 8; ++r) {
        const size_t row = (size_t)blockIdx.x * 8 + r;
        const float inv = 1.f / (rowsum[row] + EPSN);
        float4* p = (float4*)(Ul + row * (size_t)nq * 4);
        for (int i = threadIdx.x; i < nq; i += 256) {
            float4 v = p[i];
            v.x *= inv; v.y *= inv; v.z *= inv; v.w *= inv;
            p[i] = v;
        }
    }
}

// ---------- launch ----------
static inline size_t align256(size_t x) { return (x + 255) & ~(size_t)255; }

extern "C" void kernel_launch(void* const* d_in, const int* in_sizes, int n_in,
                              void* d_out, int out_size, void* d_ws, size_t ws_size,
                              hipStream_t stream) {
    const float* x        = (const float*)d_in[0];
    const float* w        = (const float*)d_in[1];
    const float* logprior = (const float*)d_in[2];
    const float* lamb     = (const float*)d_in[3];
    const int OUT = in_sizes[2];                // 2048
    const int IN  = in_sizes[1] / OUT;          // 2048
    const int B   = in_sizes[0] / IN;           // 16384
    float* out = (float*)d_out;

    char* ws = (char*)d_ws;
    size_t off = 0;
    u16* xn = (u16*)(ws + off);         off += align256((size_t)B * IN * sizeof(u16));
    u16* wn = (u16*)(ws + off);         off += align256((size_t)OUT * IN * sizeof(u16));
    float* rowsum = (float*)(ws + off); off += align256((size_t)B * sizeof(float));

    hipMemsetAsync(rowsum, 0, (size_t)B * sizeof(float), stream);

    const int nrt = B + OUT;
    normalize_cast2<<<(nrt + 3) / 4, 256, 0, stream>>>(x, w, xn, wn, IN, B, nrt);

    dim3 grid(OUT / 128, B / 128);
    gemm_softhebb<<<grid, 256, 0, stream>>>(xn, wn, logprior, lamb, out, rowsum, B, OUT, IN);

    finalize_row<<<B / 8, 256, 0, stream>>>(out, rowsum, OUT / 4);
}